// Round 1
// baseline (1631.566 us; speedup 1.0000x reference)
//
#include <hip/hip_runtime.h>
#include <math.h>

#define IMG_W 512
#define IMG_H 512
#define N_BATCH 32
#define N_ANGLES 180

// ---------------------------------------------------------------------------
// Transpose x[n][y][x] (N,1,H,W) -> xt[y*W+x][n]  (pixel-major, batch inner)
// so that per-pixel batch values are 128 B contiguous.
// Block: 256 threads handles 64 consecutive pixels x 32 batch.
// ---------------------------------------------------------------------------
__global__ __launch_bounds__(256) void transpose_kernel(
    const float* __restrict__ x, float* __restrict__ xt) {
    __shared__ float lds[64 * 33];  // +1 pad per pixel row of 32 -> conflict-free
    const int p0  = blockIdx.x * 64;          // first pixel of this block
    const int t   = threadIdx.x;
    const int pix = t & 63;
    const int nb  = t >> 6;                   // 0..3

    #pragma unroll
    for (int k = 0; k < 8; ++k) {
        const int n = nb + 4 * k;             // 0..31
        lds[pix * 33 + n] = x[(size_t)n * (IMG_W * IMG_H) + p0 + pix];
    }
    __syncthreads();
    #pragma unroll
    for (int k = 0; k < 8; ++k) {
        const int e  = t + 256 * k;           // 0..2047
        const int pp = e >> 5;
        const int n  = e & 31;
        xt[(size_t)p0 * 32 + e] = lds[pp * 33 + n];
    }
}

// ---------------------------------------------------------------------------
// Main radon kernel (transposed layout).
// Block = one (j, a) pair. 256 threads: nq = t&7 (batch quad, n = 4*nq..4*nq+3),
// ig = t>>3 in [0,32) (i-group); each thread does i = ig + 32*k, k<16.
// Each bilinear tap load is a float4 covering 4 batch images (coalesced:
// 8 lanes * 16 B = full 128 B pixel record).
// ---------------------------------------------------------------------------
__global__ __launch_bounds__(256) void radon_xt(
    const float* __restrict__ xt, float* __restrict__ out) {
    const int j = blockIdx.x;     // detector (fast dim -> adjacent blocks share band)
    const int a = blockIdx.y;     // angle
    const int t = threadIdx.x;
    const int nq = t & 7;
    const int ig = t >> 3;

    const float theta = (float)a * (float)(M_PI / 180.0);
    float s, c;
    sincosf(theta, &s, &c);

    const float cj = ((float)j + 0.5f) * (2.0f / 512.0f) - 1.0f;
    const float4* __restrict__ base = (const float4*)xt;  // pixel p -> base[p*8 + nq]

    float4 acc = make_float4(0.f, 0.f, 0.f, 0.f);

    #pragma unroll 4
    for (int k = 0; k < 16; ++k) {
        const int i = ig + 32 * k;
        const float ci = ((float)i + 0.5f) * (2.0f / 512.0f) - 1.0f;
        const float gx =  c * cj + s * ci;
        const float gy = -s * cj + c * ci;
        const float ix = ((gx + 1.0f) * 512.0f - 1.0f) * 0.5f;
        const float iy = ((gy + 1.0f) * 512.0f - 1.0f) * 0.5f;

        const float ix0f = floorf(ix);
        const float iy0f = floorf(iy);
        const float wx1 = ix - ix0f, wy1 = iy - iy0f;
        const float wx0 = 1.0f - wx1, wy0 = 1.0f - wy1;

        // validity folded into weights (zero outside)
        const float mx0 = (ix0f >=  0.0f && ix0f <= 511.0f) ? wx0 : 0.0f;
        const float mx1 = (ix0f >= -1.0f && ix0f <= 510.0f) ? wx1 : 0.0f;
        const float my0 = (iy0f >=  0.0f && iy0f <= 511.0f) ? wy0 : 0.0f;
        const float my1 = (iy0f >= -1.0f && iy0f <= 510.0f) ? wy1 : 0.0f;

        int ix0 = (int)ix0f, iy0 = (int)iy0f;
        const int x0 = min(max(ix0, 0), 511);
        const int x1 = min(max(ix0 + 1, 0), 511);
        const int y0 = min(max(iy0, 0), 511);
        const int y1 = min(max(iy0 + 1, 0), 511);

        const int r0 = y0 * 512, r1 = y1 * 512;
        const float4 t00 = base[(size_t)(r0 + x0) * 8 + nq];
        const float4 t01 = base[(size_t)(r0 + x1) * 8 + nq];
        const float4 t10 = base[(size_t)(r1 + x0) * 8 + nq];
        const float4 t11 = base[(size_t)(r1 + x1) * 8 + nq];

        const float w00 = my0 * mx0, w01 = my0 * mx1;
        const float w10 = my1 * mx0, w11 = my1 * mx1;

        acc.x = fmaf(w00, t00.x, acc.x); acc.x = fmaf(w01, t01.x, acc.x);
        acc.x = fmaf(w10, t10.x, acc.x); acc.x = fmaf(w11, t11.x, acc.x);
        acc.y = fmaf(w00, t00.y, acc.y); acc.y = fmaf(w01, t01.y, acc.y);
        acc.y = fmaf(w10, t10.y, acc.y); acc.y = fmaf(w11, t11.y, acc.y);
        acc.z = fmaf(w00, t00.z, acc.z); acc.z = fmaf(w01, t01.z, acc.z);
        acc.z = fmaf(w10, t10.z, acc.z); acc.z = fmaf(w11, t11.z, acc.z);
        acc.w = fmaf(w00, t00.w, acc.w); acc.w = fmaf(w01, t01.w, acc.w);
        acc.w = fmaf(w10, t10.w, acc.w); acc.w = fmaf(w11, t11.w, acc.w);
    }

    // reduce over ig. Within a wave: lanes with same nq are 8 apart.
    #pragma unroll
    for (int off = 32; off >= 8; off >>= 1) {
        acc.x += __shfl_down(acc.x, off, 64);
        acc.y += __shfl_down(acc.y, off, 64);
        acc.z += __shfl_down(acc.z, off, 64);
        acc.w += __shfl_down(acc.w, off, 64);
    }

    __shared__ float4 red[4][8];
    const int wave = t >> 6;
    if ((t & 63) < 8) red[wave][t & 7] = acc;
    __syncthreads();

    if (t < 8) {
        float4 r0 = red[0][t], r1 = red[1][t], r2 = red[2][t], r3 = red[3][t];
        const float v0 = r0.x + r1.x + r2.x + r3.x;
        const float v1 = r0.y + r1.y + r2.y + r3.y;
        const float v2 = r0.z + r1.z + r2.z + r3.z;
        const float v3 = r0.w + r1.w + r2.w + r3.w;
        const int n0 = t * 4;
        out[((size_t)(n0 + 0) * 512 + j) * 180 + a] = v0;
        out[((size_t)(n0 + 1) * 512 + j) * 180 + a] = v1;
        out[((size_t)(n0 + 2) * 512 + j) * 180 + a] = v2;
        out[((size_t)(n0 + 3) * 512 + j) * 180 + a] = v3;
    }
}

// ---------------------------------------------------------------------------
// Fallback (ws too small): gather directly from x[n][y][x]. Correct, slower.
// 256 threads: n = t&31, ig = t>>5 in [0,8); i = ig + 8*k, k<64.
// ---------------------------------------------------------------------------
__global__ __launch_bounds__(256) void radon_direct(
    const float* __restrict__ x, float* __restrict__ out) {
    const int j = blockIdx.x;
    const int a = blockIdx.y;
    const int t = threadIdx.x;
    const int n = t & 31;
    const int ig = t >> 5;

    const float theta = (float)a * (float)(M_PI / 180.0);
    float s, c;
    sincosf(theta, &s, &c);
    const float cj = ((float)j + 0.5f) * (2.0f / 512.0f) - 1.0f;
    const float* __restrict__ img = x + (size_t)n * (IMG_W * IMG_H);

    float acc = 0.f;
    for (int k = 0; k < 64; ++k) {
        const int i = ig + 8 * k;
        const float ci = ((float)i + 0.5f) * (2.0f / 512.0f) - 1.0f;
        const float gx =  c * cj + s * ci;
        const float gy = -s * cj + c * ci;
        const float ix = ((gx + 1.0f) * 512.0f - 1.0f) * 0.5f;
        const float iy = ((gy + 1.0f) * 512.0f - 1.0f) * 0.5f;
        const float ix0f = floorf(ix), iy0f = floorf(iy);
        const float wx1 = ix - ix0f, wy1 = iy - iy0f;
        const float wx0 = 1.0f - wx1, wy0 = 1.0f - wy1;
        const float mx0 = (ix0f >=  0.0f && ix0f <= 511.0f) ? wx0 : 0.0f;
        const float mx1 = (ix0f >= -1.0f && ix0f <= 510.0f) ? wx1 : 0.0f;
        const float my0 = (iy0f >=  0.0f && iy0f <= 511.0f) ? wy0 : 0.0f;
        const float my1 = (iy0f >= -1.0f && iy0f <= 510.0f) ? wy1 : 0.0f;
        const int ix0 = (int)ix0f, iy0 = (int)iy0f;
        const int x0 = min(max(ix0, 0), 511);
        const int x1 = min(max(ix0 + 1, 0), 511);
        const int y0 = min(max(iy0, 0), 511);
        const int y1 = min(max(iy0 + 1, 0), 511);
        acc = fmaf(my0 * mx0, img[y0 * 512 + x0], acc);
        acc = fmaf(my0 * mx1, img[y0 * 512 + x1], acc);
        acc = fmaf(my1 * mx0, img[y1 * 512 + x0], acc);
        acc = fmaf(my1 * mx1, img[y1 * 512 + x1], acc);
    }

    acc += __shfl_down(acc, 32, 64);  // combine ig pairs within wave
    __shared__ float red[4][32];
    const int wave = t >> 6;
    if ((t & 63) < 32) red[wave][t & 31] = acc;
    __syncthreads();
    if (t < 32) {
        const float v = red[0][t] + red[1][t] + red[2][t] + red[3][t];
        out[((size_t)t * 512 + j) * 180 + a] = v;
    }
}

extern "C" void kernel_launch(void* const* d_in, const int* in_sizes, int n_in,
                              void* d_out, int out_size, void* d_ws, size_t ws_size,
                              hipStream_t stream) {
    const float* x = (const float*)d_in[0];
    float* out = (float*)d_out;

    const size_t xt_bytes = (size_t)IMG_W * IMG_H * N_BATCH * sizeof(float);
    if (ws_size >= xt_bytes) {
        float* xt = (float*)d_ws;
        transpose_kernel<<<(IMG_W * IMG_H) / 64, 256, 0, stream>>>(x, xt);
        dim3 grid(IMG_W, N_ANGLES);
        radon_xt<<<grid, 256, 0, stream>>>(xt, out);
    } else {
        dim3 grid(IMG_W, N_ANGLES);
        radon_direct<<<grid, 256, 0, stream>>>(x, out);
    }
}

// Round 2
// 600.040 us; speedup vs baseline: 2.7191x; 2.7191x over previous
//
#include <hip/hip_runtime.h>
#include <hip/hip_fp16.h>
#include <math.h>

#define IMG_W 512
#define IMG_H 512
#define N_BATCH 32
#define N_ANGLES 180

// ---------------------------------------------------------------------------
// Convert + transpose: x[n][y][x] (fp32) -> xh[y*W+x][n] (fp16, 64 B / pixel
// record). Block: 256 threads handles 64 consecutive pixels x 32 batch.
// ---------------------------------------------------------------------------
__global__ __launch_bounds__(256) void convert_transpose(
    const float* __restrict__ x, __half* __restrict__ xh) {
    __shared__ float lds[64 * 33];  // +1 pad -> conflict-free
    const int p0  = blockIdx.x * 64;
    const int t   = threadIdx.x;
    const int pix = t & 63;
    const int nb  = t >> 6;  // 0..3

    #pragma unroll
    for (int k = 0; k < 8; ++k) {
        const int n = nb + 4 * k;  // 0..31
        lds[pix * 33 + n] = x[(size_t)n * (IMG_W * IMG_H) + p0 + pix];
    }
    __syncthreads();

    // thread t writes halves [t*8, t*8+8) of this block's 2048-half record:
    // pixel pp = t>>2, batch n0 = (t&3)*8 .. +8
    const int pp = t >> 2;
    const int n0 = (t & 3) * 8;
    float f[8];
    #pragma unroll
    for (int m = 0; m < 8; ++m) f[m] = lds[pp * 33 + n0 + m];
    uint4 w;
    {
        __half2 h0 = __floats2half2_rn(f[0], f[1]);
        __half2 h1 = __floats2half2_rn(f[2], f[3]);
        __half2 h2 = __floats2half2_rn(f[4], f[5]);
        __half2 h3 = __floats2half2_rn(f[6], f[7]);
        w.x = *reinterpret_cast<unsigned int*>(&h0);
        w.y = *reinterpret_cast<unsigned int*>(&h1);
        w.z = *reinterpret_cast<unsigned int*>(&h2);
        w.w = *reinterpret_cast<unsigned int*>(&h3);
    }
    reinterpret_cast<uint4*>(xh + (size_t)p0 * 32)[t] = w;
}

// ---------------------------------------------------------------------------
// Main radon kernel, fp16 transposed layout, XCD-pinned 1-D grid.
// gid decode: jb = gid&7 (XCD strip), rest = gid>>3, a = rest>>6, jr = rest&63,
// j = jb*64 + jr  ->  blockIdx%8 == j>>6, angles processed in order per XCD.
// Threads: nq = t&3 (batch octet n = nq*8..+8, one uint4 = 16 B tap),
// ig = t>>2 in [0,64); i = ig + 64*k, k<8.
// Tap load: 4 lanes x 16 B = full 64 B pixel record, coalesced.
// ---------------------------------------------------------------------------
__device__ __forceinline__ void fma8(float* acc, const uint4 v, const float w) {
    const __half2* h = reinterpret_cast<const __half2*>(&v);
    #pragma unroll
    for (int m = 0; m < 4; ++m) {
        const float2 f = __half22float2(h[m]);
        acc[2 * m]     = fmaf(w, f.x, acc[2 * m]);
        acc[2 * m + 1] = fmaf(w, f.y, acc[2 * m + 1]);
    }
}

__global__ __launch_bounds__(256) void radon_xh(
    const uint4* __restrict__ xh, float* __restrict__ out) {
    const int gid  = blockIdx.x;
    const int jb   = gid & 7;
    const int rest = gid >> 3;
    const int a    = rest >> 6;
    const int jr   = rest & 63;
    const int j    = (jb << 6) | jr;

    const int t  = threadIdx.x;
    const int nq = t & 3;
    const int ig = t >> 2;

    const float theta = (float)a * (float)(M_PI / 180.0);
    float s, c;
    sincosf(theta, &s, &c);
    const float cj = ((float)j + 0.5f) * (2.0f / 512.0f) - 1.0f;

    float acc[8] = {0.f, 0.f, 0.f, 0.f, 0.f, 0.f, 0.f, 0.f};

    #pragma unroll 2
    for (int k = 0; k < 8; ++k) {
        const int i = ig + 64 * k;
        const float ci = ((float)i + 0.5f) * (2.0f / 512.0f) - 1.0f;
        const float gx =  c * cj + s * ci;
        const float gy = -s * cj + c * ci;
        const float ix = ((gx + 1.0f) * 512.0f - 1.0f) * 0.5f;
        const float iy = ((gy + 1.0f) * 512.0f - 1.0f) * 0.5f;

        const float ix0f = floorf(ix);
        const float iy0f = floorf(iy);
        const float wx1 = ix - ix0f, wy1 = iy - iy0f;
        const float wx0 = 1.0f - wx1, wy0 = 1.0f - wy1;

        const float mx0 = (ix0f >=  0.0f && ix0f <= 511.0f) ? wx0 : 0.0f;
        const float mx1 = (ix0f >= -1.0f && ix0f <= 510.0f) ? wx1 : 0.0f;
        const float my0 = (iy0f >=  0.0f && iy0f <= 511.0f) ? wy0 : 0.0f;
        const float my1 = (iy0f >= -1.0f && iy0f <= 510.0f) ? wy1 : 0.0f;

        const int ix0 = (int)ix0f, iy0 = (int)iy0f;
        const int x0 = min(max(ix0, 0), 511);
        const int x1 = min(max(ix0 + 1, 0), 511);
        const int y0 = min(max(iy0, 0), 511);
        const int y1 = min(max(iy0 + 1, 0), 511);

        const int r0 = y0 * 512, r1 = y1 * 512;
        const uint4 t00 = xh[(r0 + x0) * 4 + nq];
        const uint4 t01 = xh[(r0 + x1) * 4 + nq];
        const uint4 t10 = xh[(r1 + x0) * 4 + nq];
        const uint4 t11 = xh[(r1 + x1) * 4 + nq];

        fma8(acc, t00, my0 * mx0);
        fma8(acc, t01, my0 * mx1);
        fma8(acc, t10, my1 * mx0);
        fma8(acc, t11, my1 * mx1);
    }

    // reduce over ig: lanes with same nq are 4 apart; 16 ig per wave
    #pragma unroll
    for (int off = 32; off >= 4; off >>= 1) {
        #pragma unroll
        for (int m = 0; m < 8; ++m) acc[m] += __shfl_down(acc[m], off, 64);
    }

    __shared__ float red[4][4][8];  // [wave][nq][batch-in-octet]
    const int wave = t >> 6;
    if ((t & 63) < 4) {
        #pragma unroll
        for (int m = 0; m < 8; ++m) red[wave][t & 3][m] = acc[m];
    }
    __syncthreads();

    if (t < 32) {
        const int oq = t >> 3, m = t & 7;
        const float v = red[0][oq][m] + red[1][oq][m] + red[2][oq][m] + red[3][oq][m];
        out[((size_t)t * 512 + j) * 180 + a] = v;
    }
}

// ---------------------------------------------------------------------------
// Fallback (ws too small): gather directly from x[n][y][x], fp32.
// ---------------------------------------------------------------------------
__global__ __launch_bounds__(256) void radon_direct(
    const float* __restrict__ x, float* __restrict__ out) {
    const int j = blockIdx.x;
    const int a = blockIdx.y;
    const int t = threadIdx.x;
    const int n = t & 31;
    const int ig = t >> 5;

    const float theta = (float)a * (float)(M_PI / 180.0);
    float s, c;
    sincosf(theta, &s, &c);
    const float cj = ((float)j + 0.5f) * (2.0f / 512.0f) - 1.0f;
    const float* __restrict__ img = x + (size_t)n * (IMG_W * IMG_H);

    float acc = 0.f;
    for (int k = 0; k < 64; ++k) {
        const int i = ig + 8 * k;
        const float ci = ((float)i + 0.5f) * (2.0f / 512.0f) - 1.0f;
        const float gx =  c * cj + s * ci;
        const float gy = -s * cj + c * ci;
        const float ix = ((gx + 1.0f) * 512.0f - 1.0f) * 0.5f;
        const float iy = ((gy + 1.0f) * 512.0f - 1.0f) * 0.5f;
        const float ix0f = floorf(ix), iy0f = floorf(iy);
        const float wx1 = ix - ix0f, wy1 = iy - iy0f;
        const float wx0 = 1.0f - wx1, wy0 = 1.0f - wy1;
        const float mx0 = (ix0f >=  0.0f && ix0f <= 511.0f) ? wx0 : 0.0f;
        const float mx1 = (ix0f >= -1.0f && ix0f <= 510.0f) ? wx1 : 0.0f;
        const float my0 = (iy0f >=  0.0f && iy0f <= 511.0f) ? wy0 : 0.0f;
        const float my1 = (iy0f >= -1.0f && iy0f <= 510.0f) ? wy1 : 0.0f;
        const int ix0 = (int)ix0f, iy0 = (int)iy0f;
        const int x0 = min(max(ix0, 0), 511);
        const int x1 = min(max(ix0 + 1, 0), 511);
        const int y0 = min(max(iy0, 0), 511);
        const int y1 = min(max(iy0 + 1, 0), 511);
        acc = fmaf(my0 * mx0, img[y0 * 512 + x0], acc);
        acc = fmaf(my0 * mx1, img[y0 * 512 + x1], acc);
        acc = fmaf(my1 * mx0, img[y1 * 512 + x0], acc);
        acc = fmaf(my1 * mx1, img[y1 * 512 + x1], acc);
    }

    acc += __shfl_down(acc, 32, 64);
    __shared__ float red[4][32];
    const int wave = t >> 6;
    if ((t & 63) < 32) red[wave][t & 31] = acc;
    __syncthreads();
    if (t < 32) {
        const float v = red[0][t] + red[1][t] + red[2][t] + red[3][t];
        out[((size_t)t * 512 + j) * 180 + a] = v;
    }
}

extern "C" void kernel_launch(void* const* d_in, const int* in_sizes, int n_in,
                              void* d_out, int out_size, void* d_ws, size_t ws_size,
                              hipStream_t stream) {
    const float* x = (const float*)d_in[0];
    float* out = (float*)d_out;

    const size_t xh_bytes = (size_t)IMG_W * IMG_H * N_BATCH * sizeof(__half);
    if (ws_size >= xh_bytes) {
        __half* xh = (__half*)d_ws;
        convert_transpose<<<(IMG_W * IMG_H) / 64, 256, 0, stream>>>(x, xh);
        radon_xh<<<IMG_W * N_ANGLES, 256, 0, stream>>>((const uint4*)xh, out);
    } else {
        dim3 grid(IMG_W, N_ANGLES);
        radon_direct<<<grid, 256, 0, stream>>>(x, out);
    }
}

// Round 4
// 455.301 us; speedup vs baseline: 3.5835x; 1.3179x over previous
//
#include <hip/hip_runtime.h>
#include <hip/hip_fp16.h>
#include <math.h>

#define IMG 512
#define NB 32
#define NA 180

typedef _Float16 h2 __attribute__((ext_vector_type(2)));
typedef __fp16  f16x2 __attribute__((ext_vector_type(2)));

__device__ __forceinline__ h2 pack2(float a, float b) {
    f16x2 r = __builtin_amdgcn_cvt_pkrtz(a, b);
    return __builtin_bit_cast(h2, r);
}

__device__ __forceinline__ float dot2f(h2 a, h2 b, float c) {
#if __has_builtin(__builtin_amdgcn_fdot2)
    return __builtin_amdgcn_fdot2(a, b, c, false);
#else
    return c + (float)a.x * (float)b.x + (float)a.y * (float)b.y;
#endif
}

// ---------------------------------------------------------------------------
// Build pair layout: xp[y*512+x] is a 128 B record of 32 half2:
//   slot n = ( v[n][y][x], v[n][y][min(x+1,511)] )
// Grid: 4096 blocks x 256 thr; thread (q = t&3, r = b*64 + t>>2) writes
// 2 uint4 = slots q*8 .. q*8+8.
// ---------------------------------------------------------------------------
__global__ __launch_bounds__(256) void build_pairs(
    const float* __restrict__ x, uint4* __restrict__ xp) {
    const int t = threadIdx.x;
    const int q = t & 3;
    const int r = blockIdx.x * 64 + (t >> 2);      // pixel index y*512+x
    const int xx = r & 511;
    const int step = (xx == 511) ? 0 : 1;
    const float* p = x + (size_t)(q * 8) * (IMG * IMG) + r;

    unsigned int wv[8];
    #pragma unroll
    for (int m = 0; m < 8; ++m) {
        const float a = p[(size_t)m * (IMG * IMG)];
        const float b = p[(size_t)m * (IMG * IMG) + step];
        __half2 hv = __floats2half2_rn(a, b);
        wv[m] = *reinterpret_cast<unsigned int*>(&hv);
    }
    uint4 w0 = make_uint4(wv[0], wv[1], wv[2], wv[3]);
    uint4 w1 = make_uint4(wv[4], wv[5], wv[6], wv[7]);
    xp[(size_t)r * 8 + q * 2]     = w0;
    xp[(size_t)r * 8 + q * 2 + 1] = w1;
}

// ---------------------------------------------------------------------------
// Main radon kernel on the pair layout.
// gid decode (XCD-pinned, 32-j strips): jb8 = gid&7 selects XCD; per XCD the
// ascending-gid order is (strip-half sl, angle a, jr) so each XCD streams
// angles in order over a resident 32-j band (~2-3 MB, fits 4 MB XCD L2).
// Threads: nq = t&3 (n = nq*8..+8), ig = t>>2 in [0,64); i = ig + 64*k, k<8.
// ix = P + i*s, iy = Q + i*c (exact linear recurrences of the ref coords).
// ---------------------------------------------------------------------------
template <bool STAGED>
__global__ __launch_bounds__(256) void radon_pair(
    const uint4* __restrict__ xp, float* __restrict__ dst) {
    const int gid = blockIdx.x;
    const int jb8 = gid & 7;
    const int r_  = gid >> 3;
    const int jr  = r_ & 31;
    const int r2  = r_ >> 5;
    const int a   = r2 % NA;
    const int sl  = r2 / NA;                     // 0 or 1
    const int j   = (((sl << 3) | jb8) << 5) | jr;

    const int t  = threadIdx.x;
    const int nq = t & 3;
    const int ig = t >> 2;

    const float theta = (float)a * (float)(M_PI / 180.0);
    float s, c;
    sincosf(theta, &s, &c);
    const float cj = ((float)j + 0.5f) * (2.0f / 512.0f) - 1.0f;
    // ix = 256*gx + 255.5 ; gx = c*cj + s*ci ; ci = (i+0.5)/256 - 1
    const float P = 256.0f * c * cj + s * (0.5f - 256.0f) + 255.5f;
    const float Q = -256.0f * s * cj + c * (0.5f - 256.0f) + 255.5f;

    float acc[8] = {0.f, 0.f, 0.f, 0.f, 0.f, 0.f, 0.f, 0.f};
    float fi = (float)ig;

    #pragma unroll
    for (int k = 0; k < 8; ++k, fi += 64.0f) {
        const float ix = fmaf(fi, s, P);
        const float iy = fmaf(fi, c, Q);
        const float ix0f = floorf(ix), iy0f = floorf(iy);
        const float wx1 = ix - ix0f, wy1 = iy - iy0f;
        const float wx0 = 1.0f - wx1, wy0 = 1.0f - wy1;

        const float mx0 = (ix0f >= 0.0f && ix0f <= 511.0f) ? wx0 : 0.0f;
        const float mx1 = (ix0f >= -1.0f && ix0f <= 510.0f) ? wx1 : 0.0f;
        const float my0 = (iy0f >= 0.0f && iy0f <= 511.0f) ? wy0 : 0.0f;
        const float my1 = (iy0f >= -1.0f && iy0f <= 510.0f) ? wy1 : 0.0f;

        // pair-slot weights; record xr=clamp(ix0) holds (v[xr], v[xr+1]).
        // ix0 == -1: the x1 tap (weight mx1) sits in the FIRST slot of rec 0.
        const bool neg = ix0f < 0.0f;
        const float wa = neg ? mx1 : mx0;
        const float wb = neg ? 0.0f : mx1;
        const h2 w0 = pack2(my0 * wa, my0 * wb);
        const h2 w1 = pack2(my1 * wa, my1 * wb);

        const int ix0 = (int)ix0f;
        const int iy0 = (int)iy0f;
        const int xr = min(max(ix0, 0), 511);
        const int y0 = min(max(iy0, 0), 511);
        const int y1 = min(max(iy0 + 1, 0), 511);

        const uint4* p0 = xp + (((y0 << 9) + xr) << 3) + (nq << 1);
        const uint4* p1 = xp + (((y1 << 9) + xr) << 3) + (nq << 1);
        const uint4 A0 = p0[0], A1 = p0[1];
        const uint4 B0 = p1[0], B1 = p1[1];
        const h2* ha0 = reinterpret_cast<const h2*>(&A0);
        const h2* ha1 = reinterpret_cast<const h2*>(&A1);
        const h2* hb0 = reinterpret_cast<const h2*>(&B0);
        const h2* hb1 = reinterpret_cast<const h2*>(&B1);

        #pragma unroll
        for (int m = 0; m < 4; ++m) {
            acc[m]     = dot2f(ha0[m], w0, acc[m]);
            acc[m]     = dot2f(hb0[m], w1, acc[m]);
            acc[m + 4] = dot2f(ha1[m], w0, acc[m + 4]);
            acc[m + 4] = dot2f(hb1[m], w1, acc[m + 4]);
        }
    }

    // reduce over ig: lanes with the same nq are 4 apart (16 per wave)
    #pragma unroll
    for (int off = 32; off >= 4; off >>= 1) {
        #pragma unroll
        for (int m = 0; m < 8; ++m) acc[m] += __shfl_down(acc[m], off, 64);
    }

    __shared__ float red[4][4][8];  // [wave][nq][m]
    const int wave = t >> 6;
    if ((t & 63) < 4) {
        #pragma unroll
        for (int m = 0; m < 8; ++m) red[wave][t & 3][m] = acc[m];
    }
    __syncthreads();

    if (t < 32) {  // n == t (oq = t>>3 matches nq*8 + m ordering)
        const int oq = t >> 3, m = t & 7;
        const float v = red[0][oq][m] + red[1][oq][m] + red[2][oq][m] + red[3][oq][m];
        if (STAGED) dst[((size_t)a * 512 + j) * 32 + t] = v;               // ws2[a][j][n]
        else        dst[((size_t)t * 512 + j) * 180 + a] = v;              // direct scatter
    }
}

// ---------------------------------------------------------------------------
// ws2[a][j][n] -> out[n][j][a]. One block per j.
// ---------------------------------------------------------------------------
__global__ __launch_bounds__(256) void sino_transpose(
    const float* __restrict__ ws2, float* __restrict__ out) {
    __shared__ float buf[NA * 33];
    const int j = blockIdx.x;
    const int t = threadIdx.x;
    for (int e = t; e < NA * 32; e += 256) {
        const int aa = e >> 5, n = e & 31;
        buf[aa * 33 + n] = ws2[((size_t)aa * 512 + j) * 32 + n];
    }
    __syncthreads();
    for (int e = t; e < NA * 32; e += 256) {
        const int n = e / NA, aa = e - n * NA;
        out[((size_t)n * 512 + j) * NA + aa] = buf[aa * 33 + n];
    }
}

// ---------------------------------------------------------------------------
// Fallback (ws too small): gather directly from x[n][y][x], fp32.
// ---------------------------------------------------------------------------
__global__ __launch_bounds__(256) void radon_direct(
    const float* __restrict__ x, float* __restrict__ out) {
    const int j = blockIdx.x;
    const int a = blockIdx.y;
    const int t = threadIdx.x;
    const int n = t & 31;
    const int ig = t >> 5;

    const float theta = (float)a * (float)(M_PI / 180.0);
    float s, c;
    sincosf(theta, &s, &c);
    const float cj = ((float)j + 0.5f) * (2.0f / 512.0f) - 1.0f;
    const float* __restrict__ img = x + (size_t)n * (IMG * IMG);

    float acc = 0.f;
    for (int k = 0; k < 64; ++k) {
        const int i = ig + 8 * k;
        const float ci = ((float)i + 0.5f) * (2.0f / 512.0f) - 1.0f;
        const float gx =  c * cj + s * ci;
        const float gy = -s * cj + c * ci;
        const float ix = ((gx + 1.0f) * 512.0f - 1.0f) * 0.5f;
        const float iy = ((gy + 1.0f) * 512.0f - 1.0f) * 0.5f;
        const float ix0f = floorf(ix), iy0f = floorf(iy);
        const float wx1 = ix - ix0f, wy1 = iy - iy0f;
        const float wx0 = 1.0f - wx1, wy0 = 1.0f - wy1;
        const float mx0 = (ix0f >=  0.0f && ix0f <= 511.0f) ? wx0 : 0.0f;
        const float mx1 = (ix0f >= -1.0f && ix0f <= 510.0f) ? wx1 : 0.0f;
        const float my0 = (iy0f >=  0.0f && iy0f <= 511.0f) ? wy0 : 0.0f;
        const float my1 = (iy0f >= -1.0f && iy0f <= 510.0f) ? wy1 : 0.0f;
        const int ix0 = (int)ix0f, iy0 = (int)iy0f;
        const int x0 = min(max(ix0, 0), 511);
        const int x1 = min(max(ix0 + 1, 0), 511);
        const int y0 = min(max(iy0, 0), 511);
        const int y1 = min(max(iy0 + 1, 0), 511);
        acc = fmaf(my0 * mx0, img[y0 * 512 + x0], acc);
        acc = fmaf(my0 * mx1, img[y0 * 512 + x1], acc);
        acc = fmaf(my1 * mx0, img[y1 * 512 + x0], acc);
        acc = fmaf(my1 * mx1, img[y1 * 512 + x1], acc);
    }

    acc += __shfl_down(acc, 32, 64);
    __shared__ float red[4][32];
    const int wave = t >> 6;
    if ((t & 63) < 32) red[wave][t & 31] = acc;
    __syncthreads();
    if (t < 32) {
        const float v = red[0][t] + red[1][t] + red[2][t] + red[3][t];
        out[((size_t)t * 512 + j) * 180 + a] = v;
    }
}

extern "C" void kernel_launch(void* const* d_in, const int* in_sizes, int n_in,
                              void* d_out, int out_size, void* d_ws, size_t ws_size,
                              hipStream_t stream) {
    const float* x = (const float*)d_in[0];
    float* out = (float*)d_out;

    const size_t xp_bytes  = (size_t)IMG * IMG * 128;            // 32 MiB
    const size_t ws2_bytes = (size_t)NA * 512 * 32 * sizeof(float);  // 11.25 MiB
    const int grid_main = 2 * NA * 32 * 8;                       // 92160

    if (ws_size >= xp_bytes + ws2_bytes) {
        uint4* xp = (uint4*)d_ws;
        float* ws2 = (float*)((char*)d_ws + xp_bytes);
        build_pairs<<<(IMG * IMG) / 64, 256, 0, stream>>>(x, xp);
        radon_pair<true><<<grid_main, 256, 0, stream>>>(xp, ws2);
        sino_transpose<<<512, 256, 0, stream>>>(ws2, out);
    } else if (ws_size >= xp_bytes) {
        uint4* xp = (uint4*)d_ws;
        build_pairs<<<(IMG * IMG) / 64, 256, 0, stream>>>(x, xp);
        radon_pair<false><<<grid_main, 256, 0, stream>>>(xp, out);
    } else {
        dim3 grid(IMG, NA);
        radon_direct<<<grid, 256, 0, stream>>>(x, out);
    }
}